// Round 6
// baseline (197.038 us; speedup 1.0000x reference)
//
#include <hip/hip_runtime.h>
#include <hip/hip_bf16.h>

// Problem constants (from reference): B,T,L,R,E,F
#define B_ 8
#define T_ 16
#define L_ 128
#define R_ 1024
#define E_ 5
#define F_ 512

typedef short short8 __attribute__((ext_vector_type(8)));
typedef float floatx4 __attribute__((ext_vector_type(4)));

// fp32 -> bf16 bits, round-half-up
__device__ __forceinline__ unsigned short f2bf(float f) {
  unsigned u = __float_as_uint(f);
  return (unsigned short)((u + 0x8000u) >> 16);
}

__device__ __forceinline__ short8 pack8(floatx4 lo, floatx4 hi) {
  short8 v;
  v[0] = (short)f2bf(lo[0]); v[1] = (short)f2bf(lo[1]);
  v[2] = (short)f2bf(lo[2]); v[3] = (short)f2bf(lo[3]);
  v[4] = (short)f2bf(hi[0]); v[5] = (short)f2bf(hi[1]);
  v[6] = (short)f2bf(hi[2]); v[7] = (short)f2bf(hi[3]);
  return v;
}

// async 16B global->LDS DMA; lane i's data lands at ldsbase + i*16
__device__ __forceinline__ void stage16(const float* g, float* lds) {
  __builtin_amdgcn_global_load_lds(
      (const __attribute__((address_space(1))) void*)g,
      (__attribute__((address_space(3))) void*)lds, 16, 0, 0);
}

// pow_e(d): exps = [-3,-2,-1,1,2]; one rsqrt yields all
template <int E>
__device__ __forceinline__ float powE(float d2, float rs) {
  if (E == 0) return rs * rs * rs;
  if (E == 1) return rs * rs;
  if (E == 2) return rs;
  if (E == 3) return d2 * rs;
  return d2;
}

// ---------------------------------------------------------------------------
// Kernel 1: rot = QR(pre_rot).Q (LAPACK Householder convention), then
// new_lig[b,t,l,:] = rot[b,t] @ lig_coord[b,l] + trans[b,t].
// ---------------------------------------------------------------------------
__global__ void prep_kernel(const float* __restrict__ lig_coord,
                            const float* __restrict__ pre_rot,
                            const float* __restrict__ trans,
                            float* __restrict__ new_lig) {
  int bt = blockIdx.x;
  __shared__ float Qs[3][3];
  if (threadIdx.x == 0) {
    float a[3][3], q[3][3];
    #pragma unroll
    for (int i = 0; i < 3; ++i)
      #pragma unroll
      for (int j = 0; j < 3; ++j) {
        a[i][j] = pre_rot[(bt * 3 + i) * 3 + j];
        q[i][j] = (i == j) ? 1.f : 0.f;
      }
    for (int k = 0; k < 3; ++k) {
      float alpha = a[k][k];
      float xn2 = 0.f;
      for (int i = k + 1; i < 3; ++i) xn2 += a[i][k] * a[i][k];
      float nrm = sqrtf(alpha * alpha + xn2);
      if (xn2 > 0.f && nrm > 0.f) {
        float beta = (alpha >= 0.f) ? -nrm : nrm;
        float tau = (beta - alpha) / beta;
        float inv = 1.f / (alpha - beta);
        float v[3] = {0.f, 0.f, 0.f};
        v[k] = 1.f;
        for (int i = k + 1; i < 3; ++i) v[i] = a[i][k] * inv;
        for (int j = k; j < 3; ++j) {
          float w = 0.f;
          for (int i = k; i < 3; ++i) w += v[i] * a[i][j];
          w *= tau;
          for (int i = k; i < 3; ++i) a[i][j] -= w * v[i];
        }
        for (int i = 0; i < 3; ++i) {
          float w = 0.f;
          for (int j = k; j < 3; ++j) w += q[i][j] * v[j];
          w *= tau;
          for (int j = k; j < 3; ++j) q[i][j] -= w * v[j];
        }
      }
    }
    for (int i = 0; i < 3; ++i)
      for (int j = 0; j < 3; ++j) Qs[i][j] = q[i][j];
  }
  __syncthreads();
  int b = bt >> 4;
  int l = threadIdx.x;
  float cx = lig_coord[(b * L_ + l) * 3 + 0];
  float cy = lig_coord[(b * L_ + l) * 3 + 1];
  float cz = lig_coord[(b * L_ + l) * 3 + 2];
  float nx = Qs[0][0] * cx + Qs[0][1] * cy + Qs[0][2] * cz + trans[bt * 3 + 0];
  float ny = Qs[1][0] * cx + Qs[1][1] * cy + Qs[1][2] * cz + trans[bt * 3 + 1];
  float nz = Qs[2][0] * cx + Qs[2][1] * cy + Qs[2][2] * cz + trans[bt * 3 + 2];
  float* o = new_lig + ((size_t)bt * L_ + l) * 3;
  o[0] = nx; o[1] = ny; o[2] = nz;
}

// ---------------------------------------------------------------------------
// Kernel 2 (FUSED, 64x64 tiles): per block (b,e,rt,mt): GEMM tile
// atn_e[l0:l0+64, r0:r0+64] via DMA double-buffered LDS (8KB A + 8KB B per
// buf = 32 KB -> 5 blocks/CU, 1280 blocks; R5's 48KB/3-per-CU gave
// occupancy 19% and no cross-block overlap of the latency-bound GEMM with
// the VALU-bound epilogue). Epilogue applies pow_e(d) and reduces over r
// in-register -> p2[b,t,e*16+rt, mt*64+l].
// ---------------------------------------------------------------------------
__launch_bounds__(256)
__global__ void fused_kernel(const float* __restrict__ lig_feat,
                             const float* __restrict__ rec_feat,
                             const float* __restrict__ new_lig,
                             const float* __restrict__ rec_coord,
                             const int* __restrict__ lig_counts,
                             const int* __restrict__ rec_counts,
                             float* __restrict__ p2) {
  const int rt = blockIdx.x >> 1;   // 0..15
  const int mt = blockIdx.x & 1;    // 0..1
  const int e  = blockIdx.y;        // 0..4
  const int b  = blockIdx.z;        // 0..7
  const int r0 = rt * 64;
  const int l0 = mt * 64;
  const int tid = threadIdx.x;
  const int k80 = e * 16 + rt;
  const int recN = rec_counts[b];

  if (r0 >= recN) {             // fully masked tile: zero our p2 slice
    for (int i = tid; i < T_ * 64; i += 256) {
      int t = i >> 6, l = i & 63;
      p2[(((size_t)b * T_ + t) * 80 + k80) * L_ + l0 + l] = 0.f;
    }
    return;
  }

  __shared__ float smem[4 * 2048];                 // 32 KB
  float (*As)[2048] = (float(*)[2048])smem;        // [buf][64 rows x 32k]
  float (*Bs)[2048] = (float(*)[2048])(smem + 2 * 2048);

  const int wave = tid >> 6;
  const int lane = tid & 63;
  const int lrow = lane & 15;
  const int quad = lane >> 4;
  const int wm   = wave * 16;       // wave's local A-row base (16 rows)

  // --- staging: wave stages 16 A rows + 16 B rows per chunk (2+2 stage16).
  // 16B-chunk swizzled on the GLOBAL side (chunk ^= row&7); LDS dst linear.
  const int lr8 = lane >> 3;
  const int sw  = (lane & 7) ^ lr8;
  const float* ga[2];
  #pragma unroll
  for (int i = 0; i < 2; ++i) {
    int row = wave * 16 + i * 8 + lr8;            // local A row
    ga[i] = lig_feat + ((size_t)(b * L_ + l0 + row) * E_ + e) * F_ + sw * 4;
  }
  const float* gb[2];
  #pragma unroll
  for (int i = 0; i < 2; ++i) {
    int row = wave * 16 + i * 8 + lr8;            // local B row
    gb[i] = rec_feat + ((size_t)(b * R_ + r0 + row) * E_ + e) * F_ + sw * 4;
  }

  floatx4 acc[4];
  #pragma unroll
  for (int j = 0; j < 4; ++j) acc[j] = (floatx4){0.f, 0.f, 0.f, 0.f};

  // fragment-read physical chunks (row&7 == lane&7 for all fragment rows)
  const int c0 = (2 * quad) ^ (lane & 7);

  // stage chunk 0 -> buf 0
  #pragma unroll
  for (int i = 0; i < 2; ++i) stage16(ga[i], &As[0][(wave * 16 + i * 8) * 32]);
  #pragma unroll
  for (int i = 0; i < 2; ++i) stage16(gb[i], &Bs[0][(wave * 16 + i * 8) * 32]);
  __syncthreads();

  #pragma unroll 1
  for (int kc = 0; kc < 16; ++kc) {
    const int cur = kc & 1;
    if (kc < 15) {
      const int col = (kc + 1) * 32;
      #pragma unroll
      for (int i = 0; i < 2; ++i)
        stage16(ga[i] + col, &As[cur ^ 1][(wave * 16 + i * 8) * 32]);
      #pragma unroll
      for (int i = 0; i < 2; ++i)
        stage16(gb[i] + col, &Bs[cur ^ 1][(wave * 16 + i * 8) * 32]);
    }
    short8 af, bfv[4];
    {
      const float* base = &As[cur][(wm + lrow) * 32];
      af = pack8(*(const floatx4*)(base + c0 * 4),
                 *(const floatx4*)(base + (c0 ^ 1) * 4));
    }
    #pragma unroll
    for (int j = 0; j < 4; ++j) {
      const float* base = &Bs[cur][(j * 16 + lrow) * 32];
      bfv[j] = pack8(*(const floatx4*)(base + c0 * 4),
                     *(const floatx4*)(base + (c0 ^ 1) * 4));
    }
    #pragma unroll
    for (int j = 0; j < 4; ++j)
      acc[j] = __builtin_amdgcn_mfma_f32_16x16x32_bf16(af, bfv[j], acc[j], 0, 0, 0);
    __syncthreads();
  }

  // ---- epilogue: distance-weighted reduction over this tile's 64 r ----
  // reuse As region for this block's new_lig tile (T x 64 l, float4-padded)
  float* nls4 = smem;               // [(t*64+ll)*4], 16 KB
  for (int idx = tid; idx < T_ * 64; idx += 256) {
    int t = idx >> 6, ll = idx & 63;
    const float* src = new_lig + ((size_t)(b * T_ + t) * L_ + l0 + ll) * 3;
    nls4[idx * 4 + 0] = src[0];
    nls4[idx * 4 + 1] = src[1];
    nls4[idx * 4 + 2] = src[2];
  }
  __syncthreads();

  const int ligN = lig_counts[b];
  float rx[4], ry[4], rz[4];
  #pragma unroll
  for (int j = 0; j < 4; ++j) {
    int r = r0 + j * 16 + lrow;
    const float* rc = rec_coord + ((size_t)b * R_ + r) * 3;
    rx[j] = rc[0]; ry[j] = rc[1]; rz[j] = rc[2];
    const float rmsk = (r < recN) ? 1.f : 0.f;   // zero masked-pair atn
    acc[j] *= rmsk;
  }

  // block-uniform switch on e -> 5 instantiations
  #define EPILOGUE(EXP)                                                        \
    _Pragma("unroll 1")                                                        \
    for (int t = 0; t < T_; ++t) {                                             \
      _Pragma("unroll")                                                        \
      for (int reg = 0; reg < 4; ++reg) {                                      \
        const int ll = wm + quad * 4 + reg;                                    \
        const floatx4 nl = *(const floatx4*)&nls4[(t * 64 + ll) * 4];          \
        float val = 0.f;                                                       \
        _Pragma("unroll")                                                      \
        for (int j = 0; j < 4; ++j) {                                          \
          float dx = nl[0] - rx[j];                                            \
          float dy = nl[1] - ry[j];                                            \
          float dz = nl[2] - rz[j];                                            \
          float d2 = fmaf(dx, dx, fmaf(dy, dy, dz * dz));                      \
          d2 = fmaxf(d2, 1e-20f);                                              \
          float rs = rsqrtf(d2);                                               \
          val = fmaf(acc[j][reg], powE<EXP>(d2, rs), val);                     \
        }                                                                      \
        if (l0 + ll >= ligN) val = 0.f;                                        \
        val += __shfl_xor(val, 1, 64);                                         \
        val += __shfl_xor(val, 2, 64);                                         \
        val += __shfl_xor(val, 4, 64);                                         \
        val += __shfl_xor(val, 8, 64);                                         \
        if (lrow == 0)                                                         \
          p2[(((size_t)b * T_ + t) * 80 + k80) * L_ + l0 + ll] = val;          \
      }                                                                        \
    }

  switch (e) {
    case 0: EPILOGUE(0) break;
    case 1: EPILOGUE(1) break;
    case 2: EPILOGUE(2) break;
    case 3: EPILOGUE(3) break;
    default: EPILOGUE(4) break;
  }
  #undef EPILOGUE
}

// ---------------------------------------------------------------------------
// Kernel 3: out[b,t] = sum_{k<80, l<128} p2[b,t,k,l]
// 128 blocks x 128 threads; thread l sums its 80-slice column (coalesced).
// ---------------------------------------------------------------------------
__global__ void final_kernel(const float* __restrict__ p2,
                             float* __restrict__ out) {
  const int bt = blockIdx.x;
  const int l = threadIdx.x;
  const float* p = p2 + (size_t)bt * 80 * L_ + l;
  float v = 0.f;
  #pragma unroll
  for (int k = 0; k < 80; ++k) v += p[k * L_];
  #pragma unroll
  for (int m = 32; m > 0; m >>= 1) v += __shfl_xor(v, m, 64);
  __shared__ float s[2];
  if ((l & 63) == 0) s[l >> 6] = v;
  __syncthreads();
  if (l == 0) out[bt] = s[0] + s[1];
}

// ---------------------------------------------------------------------------
extern "C" void kernel_launch(void* const* d_in, const int* in_sizes, int n_in,
                              void* d_out, int out_size, void* d_ws, size_t ws_size,
                              hipStream_t stream) {
  const float* lig_feat   = (const float*)d_in[0];
  const float* rec_feat   = (const float*)d_in[1];
  const float* lig_coord  = (const float*)d_in[2];
  const float* rec_coord  = (const float*)d_in[3];
  const float* pre_rot    = (const float*)d_in[4];
  const float* trans      = (const float*)d_in[5];
  const int*   lig_counts = (const int*)d_in[6];
  const int*   rec_counts = (const int*)d_in[7];
  float* out = (float*)d_out;

  // ws: new_lig [B,T,L,3] (24 KB) | p2 [B,T,80,L] (5.24 MB)
  float* new_lig = (float*)d_ws;
  float* p2      = new_lig + (size_t)B_ * T_ * L_ * 3;

  prep_kernel<<<dim3(B_ * T_), dim3(L_), 0, stream>>>(lig_coord, pre_rot, trans, new_lig);
  fused_kernel<<<dim3(32, E_, B_), dim3(256), 0, stream>>>(
      lig_feat, rec_feat, new_lig, rec_coord, lig_counts, rec_counts, p2);
  final_kernel<<<dim3(B_ * T_), dim3(128), 0, stream>>>(p2, out);
}

// Round 7
// 170.068 us; speedup vs baseline: 1.1586x; 1.1586x over previous
//
#include <hip/hip_runtime.h>
#include <hip/hip_bf16.h>

// Problem constants (from reference): B,T,L,R,E,F
#define B_ 8
#define T_ 16
#define L_ 128
#define R_ 1024
#define E_ 5
#define F_ 512

typedef short short8 __attribute__((ext_vector_type(8)));
typedef float floatx4 __attribute__((ext_vector_type(4)));
typedef unsigned short ushort4v __attribute__((ext_vector_type(4)));

// fp32 -> bf16 bits, round-half-up
__device__ __forceinline__ unsigned short f2bf(float f) {
  unsigned u = __float_as_uint(f);
  return (unsigned short)((u + 0x8000u) >> 16);
}

__device__ __forceinline__ short8 pack8(floatx4 lo, floatx4 hi) {
  short8 v;
  v[0] = (short)f2bf(lo[0]); v[1] = (short)f2bf(lo[1]);
  v[2] = (short)f2bf(lo[2]); v[3] = (short)f2bf(lo[3]);
  v[4] = (short)f2bf(hi[0]); v[5] = (short)f2bf(hi[1]);
  v[6] = (short)f2bf(hi[2]); v[7] = (short)f2bf(hi[3]);
  return v;
}

// async 16B global->LDS DMA; lane i's data lands at ldsbase + i*16
__device__ __forceinline__ void stage16(const float* g, float* lds) {
  __builtin_amdgcn_global_load_lds(
      (const __attribute__((address_space(1))) void*)g,
      (__attribute__((address_space(3))) void*)lds, 16, 0, 0);
}

// s_waitcnt immediates (gfx9 encoding): lgkmcnt=15 (don't care), expcnt=7,
// vmcnt in bits [3:0] (hi bits [15:14] zero for vmcnt<16)
#define WAITCNT_VM6 0xF76   // vmcnt(6): prev chunk's 6 DMAs done, 6 newer in flight
#define WAITCNT_VM0 0xF70   // vmcnt(0)

// ---------------------------------------------------------------------------
// Kernel 1: rot = QR(pre_rot).Q (LAPACK Householder convention), then
// new_lig[b,t,l,:] = rot[b,t] @ lig_coord[b,l] + trans[b,t].
// ---------------------------------------------------------------------------
__global__ void prep_kernel(const float* __restrict__ lig_coord,
                            const float* __restrict__ pre_rot,
                            const float* __restrict__ trans,
                            float* __restrict__ new_lig) {
  int bt = blockIdx.x;
  __shared__ float Qs[3][3];
  if (threadIdx.x == 0) {
    float a[3][3], q[3][3];
    #pragma unroll
    for (int i = 0; i < 3; ++i)
      #pragma unroll
      for (int j = 0; j < 3; ++j) {
        a[i][j] = pre_rot[(bt * 3 + i) * 3 + j];
        q[i][j] = (i == j) ? 1.f : 0.f;
      }
    for (int k = 0; k < 3; ++k) {
      float alpha = a[k][k];
      float xn2 = 0.f;
      for (int i = k + 1; i < 3; ++i) xn2 += a[i][k] * a[i][k];
      float nrm = sqrtf(alpha * alpha + xn2);
      if (xn2 > 0.f && nrm > 0.f) {
        float beta = (alpha >= 0.f) ? -nrm : nrm;
        float tau = (beta - alpha) / beta;
        float inv = 1.f / (alpha - beta);
        float v[3] = {0.f, 0.f, 0.f};
        v[k] = 1.f;
        for (int i = k + 1; i < 3; ++i) v[i] = a[i][k] * inv;
        for (int j = k; j < 3; ++j) {
          float w = 0.f;
          for (int i = k; i < 3; ++i) w += v[i] * a[i][j];
          w *= tau;
          for (int i = k; i < 3; ++i) a[i][j] -= w * v[i];
        }
        for (int i = 0; i < 3; ++i) {
          float w = 0.f;
          for (int j = k; j < 3; ++j) w += q[i][j] * v[j];
          w *= tau;
          for (int j = k; j < 3; ++j) q[i][j] -= w * v[j];
        }
      }
    }
    for (int i = 0; i < 3; ++i)
      for (int j = 0; j < 3; ++j) Qs[i][j] = q[i][j];
  }
  __syncthreads();
  int b = bt >> 4;
  int l = threadIdx.x;
  float cx = lig_coord[(b * L_ + l) * 3 + 0];
  float cy = lig_coord[(b * L_ + l) * 3 + 1];
  float cz = lig_coord[(b * L_ + l) * 3 + 2];
  float nx = Qs[0][0] * cx + Qs[0][1] * cy + Qs[0][2] * cz + trans[bt * 3 + 0];
  float ny = Qs[1][0] * cx + Qs[1][1] * cy + Qs[1][2] * cz + trans[bt * 3 + 1];
  float nz = Qs[2][0] * cx + Qs[2][1] * cy + Qs[2][2] * cz + trans[bt * 3 + 2];
  float* o = new_lig + ((size_t)bt * L_ + l) * 3;
  o[0] = nx; o[1] = ny; o[2] = nz;
}

// ---------------------------------------------------------------------------
// Kernel 2: atn[b,e,l,r] (bf16) = sum_f lig_feat[b,l,e,f] * rec_feat[b,r,e,f]
// R4 mainloop but with AITER-style fine-grained sync: __syncthreads emits
// s_waitcnt vmcnt(0) which drains the just-issued prefetch every chunk
// (the m97 barrier-drain -> full HBM latency exposed per chunk). Replaced
// with raw s_barrier + manual s_waitcnt vmcnt(6): wait only for the CURRENT
// chunk's 6 DMAs, keep the next chunk's 6 in flight across the barrier.
//   iter k: [barrier: readers of buf[cur^1] retired] -> stage(k+1 -> cur^1)
//           -> vmcnt(6) (stage(k) landed) -> barrier -> ds_read/MFMA buf[cur]
// Output stored bf16 (halves WRITE + reduce's read; ~0.2% extra rounding).
// Tile: M=128 x N=64 per block (640 blocks); wave = 32M x 64N; BK=32, dbuf.
// ---------------------------------------------------------------------------
__launch_bounds__(256)
__global__ void gemm_kernel(const float* __restrict__ lig_feat,
                            const float* __restrict__ rec_feat,
                            const int* __restrict__ rec_counts,
                            unsigned short* __restrict__ atn) {
  const int rt = blockIdx.x;    // 0..15
  const int e  = blockIdx.y;    // 0..4
  const int b  = blockIdx.z;    // 0..7
  const int r0 = rt * 64;
  if (r0 >= rec_counts[b]) return;   // tile fully masked downstream (uniform)

  __shared__ float As[2][128 * 32];  // [buf][row][32k], 16B chunks swizzled
  __shared__ float Bs[2][64 * 32];

  const int tid  = threadIdx.x;
  const int wave = tid >> 6;
  const int lane = tid & 63;
  const int lrow = lane & 15;
  const int quad = lane >> 4;
  const int wm   = wave * 32;

  // staging: wave stages 8 rows/instr; 16B-chunk swizzled on the GLOBAL
  // side (chunk ^= row&7) since the DMA's LDS dst is linear base+lane*16.
  const int lr8 = lane >> 3;
  const int sw  = (lane & 7) ^ lr8;
  const float* ga[4];
  #pragma unroll
  for (int i = 0; i < 4; ++i) {
    int row = wave * 32 + i * 8 + lr8;
    ga[i] = lig_feat + ((size_t)(b * L_ + row) * E_ + e) * F_ + sw * 4;
  }
  const float* gb[2];
  #pragma unroll
  for (int i = 0; i < 2; ++i) {
    int row = wave * 16 + i * 8 + lr8;
    gb[i] = rec_feat + ((size_t)(b * R_ + r0 + row) * E_ + e) * F_ + sw * 4;
  }

  floatx4 acc[2][4];
  #pragma unroll
  for (int i = 0; i < 2; ++i)
    #pragma unroll
    for (int j = 0; j < 4; ++j)
      acc[i][j] = (floatx4){0.f, 0.f, 0.f, 0.f};

  // fragment-read physical chunks (row&7 == lane&7 for all fragment rows)
  const int c0 = (2 * quad) ^ (lane & 7);

  // stage chunk 0 -> buf 0 (6 DMA loads per wave)
  #pragma unroll
  for (int i = 0; i < 4; ++i) stage16(ga[i], &As[0][(wave * 32 + i * 8) * 32]);
  #pragma unroll
  for (int i = 0; i < 2; ++i) stage16(gb[i], &Bs[0][(wave * 16 + i * 8) * 32]);

  #pragma unroll 1
  for (int kc = 0; kc < 16; ++kc) {
    const int cur = kc & 1;
    if (kc > 0)
      __builtin_amdgcn_s_barrier();     // all waves done reading buf[cur^1]
    if (kc < 15) {                      // prefetch next chunk -> buf[cur^1]
      const int col = (kc + 1) * 32;
      #pragma unroll
      for (int i = 0; i < 4; ++i)
        stage16(ga[i] + col, &As[cur ^ 1][(wave * 32 + i * 8) * 32]);
      #pragma unroll
      for (int i = 0; i < 2; ++i)
        stage16(gb[i] + col, &Bs[cur ^ 1][(wave * 16 + i * 8) * 32]);
      __builtin_amdgcn_s_waitcnt(WAITCNT_VM6);  // stage(kc) done; 6 in flight
    } else {
      __builtin_amdgcn_s_waitcnt(WAITCNT_VM0);
    }
    __builtin_amdgcn_s_barrier();       // every wave's stage(kc) landed
    __builtin_amdgcn_sched_barrier(0);  // keep ds_reads below the barrier

    short8 af[2], bfv[4];
    #pragma unroll
    for (int i = 0; i < 2; ++i) {
      const float* base = &As[cur][(wm + i * 16 + lrow) * 32];
      af[i] = pack8(*(const floatx4*)(base + c0 * 4),
                    *(const floatx4*)(base + (c0 ^ 1) * 4));
    }
    #pragma unroll
    for (int j = 0; j < 4; ++j) {
      const float* base = &Bs[cur][(j * 16 + lrow) * 32];
      bfv[j] = pack8(*(const floatx4*)(base + c0 * 4),
                     *(const floatx4*)(base + (c0 ^ 1) * 4));
    }
    #pragma unroll
    for (int i = 0; i < 2; ++i)
      #pragma unroll
      for (int j = 0; j < 4; ++j)
        acc[i][j] = __builtin_amdgcn_mfma_f32_16x16x32_bf16(af[i], bfv[j], acc[i][j], 0, 0, 0);
  }

  // store C tile bf16: atn[((b*E+e)*L + m)*R + r0 + n]
  const size_t base = (size_t)(b * E_ + e) * L_ * R_;
  #pragma unroll
  for (int i = 0; i < 2; ++i)
    #pragma unroll
    for (int j = 0; j < 4; ++j)
      #pragma unroll
      for (int reg = 0; reg < 4; ++reg) {
        int m = wm + i * 16 + quad * 4 + reg;
        int n = j * 16 + lrow;
        atn[base + (size_t)m * R_ + r0 + n] = f2bf(acc[i][j][reg]);
      }
}

// ---------------------------------------------------------------------------
// Kernel 3: partial[b,t,l] = sum_{r,e} atn[b,e,l,r] * d(b,t,l,r)^exp[e]
// One block per (b,l), no atomics. Thread owns r=4*tid..+4: 5x8B bf16 atn
// loads + 3 float4 coord loads all issue up front, ~960 FLOP amortizes.
// Wave-uniform skip of fully-masked 256-r spans.
// ---------------------------------------------------------------------------
__launch_bounds__(256)
__global__ void reduce_kernel(const unsigned short* __restrict__ atn,
                              const float* __restrict__ new_lig,
                              const float* __restrict__ rec_coord,
                              const int* __restrict__ lig_counts,
                              const int* __restrict__ rec_counts,
                              float* __restrict__ partial) {
  const int b = blockIdx.x >> 7;
  const int l = blockIdx.x & 127;
  const int tid = threadIdx.x;
  if (l >= lig_counts[b]) {             // write zeros so final_kernel is mask-free
    if (tid < T_) partial[(size_t)(b * T_ + tid) * L_ + l] = 0.f;
    return;
  }
  const int recN = rec_counts[b];
  const int wave = tid >> 6;

  __shared__ float nl[T_][3];
  __shared__ float sm[4][T_];
  if (tid < T_ * 3)
    nl[tid / 3][tid % 3] =
        new_lig[((size_t)(b * T_ + tid / 3) * L_ + l) * 3 + (tid % 3)];
  __syncthreads();

  float u[T_];
  #pragma unroll
  for (int t = 0; t < T_; ++t) u[t] = 0.f;

  if (wave * 256 < recN) {              // wave-uniform skip of masked span
    const int r = tid * 4;
    const size_t plane = (size_t)L_ * R_;
    const unsigned short* atnB = atn + (size_t)b * E_ * plane + (size_t)l * R_ + r;
    const float* rcB = rec_coord + ((size_t)b * R_ + r) * 3;

    ushort4v a4[5];
    #pragma unroll
    for (int e = 0; e < 5; ++e) a4[e] = *(const ushort4v*)(atnB + e * plane);
    floatx4 q0 = *(const floatx4*)(rcB + 0);
    floatx4 q1 = *(const floatx4*)(rcB + 4);
    floatx4 q2 = *(const floatx4*)(rcB + 8);
    float px[4] = {q0[0], q0[3], q1[2], q2[1]};
    float py[4] = {q0[1], q1[0], q1[3], q2[2]};
    float pz[4] = {q0[2], q1[1], q2[0], q2[3]};
    float am[5][4];
    #pragma unroll
    for (int e = 0; e < 5; ++e)
      #pragma unroll
      for (int s = 0; s < 4; ++s)
        am[e][s] = (r + s < recN)
                       ? __uint_as_float((unsigned)a4[e][s] << 16)
                       : 0.f;

    #pragma unroll
    for (int t = 0; t < T_; ++t) {
      float acc = 0.f;
      #pragma unroll
      for (int s = 0; s < 4; ++s) {
        float dx = nl[t][0] - px[s];
        float dy = nl[t][1] - py[s];
        float dz = nl[t][2] - pz[s];
        float d2 = fmaf(dx, dx, fmaf(dy, dy, dz * dz));
        d2 = fmaxf(d2, 1e-20f);
        float rs  = rsqrtf(d2);
        float rs2 = rs * rs;
        float rs3 = rs2 * rs;
        float d1  = d2 * rs;
        float c = am[0][s] * rs3;
        c = fmaf(am[1][s], rs2, c);
        c = fmaf(am[2][s], rs, c);
        c = fmaf(am[3][s], d1, c);
        c = fmaf(am[4][s], d2, c);
        acc += c;
      }
      u[t] += acc;
    }
  }

  #pragma unroll
  for (int t = 0; t < T_; ++t) {
    float v = u[t];
    #pragma unroll
    for (int m = 32; m > 0; m >>= 1) v += __shfl_xor(v, m, 64);
    if ((tid & 63) == 0) sm[wave][t] = v;
  }
  __syncthreads();
  if (tid < T_)
    partial[(size_t)(b * T_ + tid) * L_ + l] =
        sm[0][tid] + sm[1][tid] + sm[2][tid] + sm[3][tid];
}

// ---------------------------------------------------------------------------
// Kernel 4: out[b,t] = sum_l partial[b,t,l]   (128 blocks x 128 threads)
// ---------------------------------------------------------------------------
__global__ void final_kernel(const float* __restrict__ partial,
                             float* __restrict__ out) {
  const int bt = blockIdx.x;
  const int l = threadIdx.x;
  float v = partial[(size_t)bt * L_ + l];
  #pragma unroll
  for (int m = 32; m > 0; m >>= 1) v += __shfl_xor(v, m, 64);
  __shared__ float s[2];
  if ((l & 63) == 0) s[l >> 6] = v;
  __syncthreads();
  if (l == 0) out[bt] = s[0] + s[1];
}

// ---------------------------------------------------------------------------
extern "C" void kernel_launch(void* const* d_in, const int* in_sizes, int n_in,
                              void* d_out, int out_size, void* d_ws, size_t ws_size,
                              hipStream_t stream) {
  const float* lig_feat   = (const float*)d_in[0];
  const float* rec_feat   = (const float*)d_in[1];
  const float* lig_coord  = (const float*)d_in[2];
  const float* rec_coord  = (const float*)d_in[3];
  const float* pre_rot    = (const float*)d_in[4];
  const float* trans      = (const float*)d_in[5];
  const int*   lig_counts = (const int*)d_in[6];
  const int*   rec_counts = (const int*)d_in[7];
  float* out = (float*)d_out;

  // ws: new_lig [B,T,L,3] f32 (192KB) | atn [B,E,L,R] bf16 (10.5MB) |
  //     partial [B,T,L] f32 (64KB)
  float* new_lig = (float*)d_ws;
  unsigned short* atn = (unsigned short*)(new_lig + (size_t)B_ * T_ * L_ * 3);
  float* partial = (float*)(atn + (size_t)B_ * E_ * L_ * R_);

  prep_kernel<<<dim3(B_ * T_), dim3(L_), 0, stream>>>(lig_coord, pre_rot, trans, new_lig);
  gemm_kernel<<<dim3(R_ / 64, E_, B_), dim3(256), 0, stream>>>(lig_feat, rec_feat,
                                                               rec_counts, atn);
  reduce_kernel<<<dim3(B_ * L_), dim3(256), 0, stream>>>(atn, new_lig, rec_coord,
                                                         lig_counts, rec_counts, partial);
  final_kernel<<<dim3(B_ * T_), dim3(128), 0, stream>>>(partial, out);
}